// Round 4
// baseline (171.319 us; speedup 1.0000x reference)
//
#include <hip/hip_runtime.h>
#include <cmath>

typedef float f4 __attribute__((ext_vector_type(4)));

#define TPB    4      // tokens per k1 group
#define NBLK1  1024   // k1 grid
#define G1     4      // groups per k1 block   (1024*4*4 = 16384 tokens)
#define TPB2   16     // tokens per k2 block
#define NBLK2  1024   // k2 grid              (1024*16  = 16384 tokens)
#define SCALEF 8.0f   // alpha/rank = 32/4

// ---------------- k1: s12[t][0..7]=router scores, [8..11]=A·x -------------
__global__ __launch_bounds__(256, 2) void k1_scores(
    const float* __restrict__ x,
    const float* __restrict__ A_w,
    const float* __restrict__ router_w,
    float* __restrict__ s12out)
{
    const int tid = threadIdx.x;
    const int b   = blockIdx.x;
    const int wid = tid >> 6, lane = tid & 63;

    const f4* __restrict__ x4 = (const f4*)x;        // [ntok][1024]
    const f4* __restrict__ r4 = (const f4*)router_w; // rows 0..7
    const f4* __restrict__ a4 = (const f4*)A_w;      // rows 8..11

    __shared__ float red[2][4][TPB * 12];

    f4 xvA[16], xvB[16];   // ping-pong x for current/next group
    f4 wbuf[3][4];         // 3-slot weight rotation, 2 rows ahead
    float acc[TPB][12];

#define ROWPTR(W) ((W) < 8 ? (r4 + (size_t)(W) * 1024) : (a4 + (size_t)((W) - 8) * 1024))

    // prologue: x for group 0 (nontemporal: never reused) + weight rows 0,1
    {
        const int tok0 = b * TPB;
#pragma unroll
        for (int tk = 0; tk < TPB; ++tk)
#pragma unroll
            for (int p = 0; p < 4; ++p)
                xvA[tk * 4 + p] = __builtin_nontemporal_load(
                    &x4[(size_t)(tok0 + tk) * 1024 + p * 256 + tid]);
    }
#pragma unroll
    for (int p = 0; p < 4; ++p) wbuf[0][p] = ROWPTR(0)[p * 256 + tid];
#pragma unroll
    for (int p = 0; p < 4; ++p) wbuf[1][p] = ROWPTR(1)[p * 256 + tid];

#define K1_GROUP(XC, XN, Q)                                                    \
  {                                                                            \
    const int tok0 = ((Q) * NBLK1 + b) * TPB;                                  \
    _Pragma("unroll")                                                          \
    for (int tk = 0; tk < TPB; ++tk)                                           \
      _Pragma("unroll")                                                        \
      for (int w = 0; w < 12; ++w) acc[tk][w] = 0.f;                           \
    /* weight stream: FMA row w while loading row w+2 (3-slot) */              \
    _Pragma("unroll")                                                          \
    for (int w = 0; w < 12; ++w) {                                             \
      if (w + 2 < 12) {                                                        \
        const f4* __restrict__ rp = ROWPTR(w + 2);                             \
        _Pragma("unroll")                                                      \
        for (int p = 0; p < 4; ++p)                                            \
          wbuf[(w + 2) % 3][p] = rp[p * 256 + tid];                            \
      }                                                                        \
      _Pragma("unroll")                                                        \
      for (int p = 0; p < 4; ++p) {                                            \
        const f4 wv = wbuf[w % 3][p];                                          \
        _Pragma("unroll")                                                      \
        for (int tk = 0; tk < TPB; ++tk) {                                     \
          acc[tk][w] = fmaf(XC[tk * 4 + p][0], wv[0], acc[tk][w]);             \
          acc[tk][w] = fmaf(XC[tk * 4 + p][1], wv[1], acc[tk][w]);             \
          acc[tk][w] = fmaf(XC[tk * 4 + p][2], wv[2], acc[tk][w]);             \
          acc[tk][w] = fmaf(XC[tk * 4 + p][3], wv[3], acc[tk][w]);             \
        }                                                                      \
      }                                                                        \
    }                                                                          \
    /* issue next group's x + weight rows 0,1 NOW; butterfly hides latency */  \
    if ((Q) + 1 < G1) {                                                        \
      const int ntok0 = (((Q) + 1) * NBLK1 + b) * TPB;                         \
      _Pragma("unroll")                                                        \
      for (int tk = 0; tk < TPB; ++tk)                                         \
        _Pragma("unroll")                                                      \
        for (int p = 0; p < 4; ++p)                                            \
          XN[tk * 4 + p] = __builtin_nontemporal_load(                         \
              &x4[(size_t)(ntok0 + tk) * 1024 + p * 256 + tid]);               \
      _Pragma("unroll")                                                        \
      for (int p = 0; p < 4; ++p) wbuf[0][p] = ROWPTR(0)[p * 256 + tid];       \
      _Pragma("unroll")                                                        \
      for (int p = 0; p < 4; ++p) wbuf[1][p] = ROWPTR(1)[p * 256 + tid];       \
    }                                                                          \
    /* wave butterfly reduction */                                             \
    _Pragma("unroll")                                                          \
    for (int tk = 0; tk < TPB; ++tk)                                           \
      _Pragma("unroll")                                                        \
      for (int w = 0; w < 12; ++w) {                                           \
        float v = acc[tk][w];                                                  \
        _Pragma("unroll")                                                      \
        for (int m = 1; m < 64; m <<= 1) v += __shfl_xor(v, m, 64);            \
        acc[tk][w] = v;                                                        \
      }                                                                        \
    if (lane == 0) {                                                           \
      _Pragma("unroll")                                                        \
      for (int tk = 0; tk < TPB; ++tk)                                         \
        _Pragma("unroll")                                                      \
        for (int w = 0; w < 12; ++w)                                           \
          red[(Q) & 1][wid][tk * 12 + w] = acc[tk][w];                         \
    }                                                                          \
    __syncthreads();                                                           \
    if (tid < TPB * 12) {                                                      \
      const float s = red[(Q) & 1][0][tid] + red[(Q) & 1][1][tid] +            \
                      red[(Q) & 1][2][tid] + red[(Q) & 1][3][tid];             \
      s12out[(size_t)tok0 * 12 + tid] = s;                                     \
    }                                                                          \
  }

    K1_GROUP(xvA, xvB, 0)
    K1_GROUP(xvB, xvA, 1)
    K1_GROUP(xvA, xvB, 2)
    K1_GROUP(xvB, xvA, 3)
#undef K1_GROUP
#undef ROWPTR
}

// ---------------- k2: epilogue + out = gelu(h)·B^T · SCALING ---------------
__global__ __launch_bounds__(256, 3) void k2_out(
    const float* __restrict__ s12,
    const float* __restrict__ B_w,
    const float* __restrict__ expert_vectors,
    float* __restrict__ out)
{
    const int tid  = threadIdx.x;
    const int tok0 = blockIdx.x * TPB2;

    __shared__ float hsh[TPB2][4];

    // B_w register cache — issue first so L2 latency hides under epilogue
    f4 Bc[4][4];
    const f4* __restrict__ b4 = (const f4*)B_w;  // row o = one f4
#pragma unroll
    for (int i = 0; i < 4; ++i)
#pragma unroll
        for (int k = 0; k < 4; ++k)
            Bc[i][k] = b4[4 * (i * 256 + tid) + k];

    // per-token epilogue: threads 0..15, one token each
    if (tid < TPB2) {
        const int t = tok0 + tid;
        float sv[12];
#pragma unroll
        for (int w = 0; w < 12; ++w) sv[w] = s12[(size_t)t * 12 + w];

        float sc[8];
#pragma unroll
        for (int e = 0; e < 8; ++e) sc[e] = sv[e];

        int   idx[4];
        float val[4];
#pragma unroll
        for (int k = 0; k < 4; ++k) {
            int bi = 0; float bv = sc[0];
#pragma unroll
            for (int e = 1; e < 8; ++e)
                if (sc[e] > bv) { bv = sc[e]; bi = e; }
            idx[k] = bi; val[k] = bv;
#pragma unroll
            for (int e = 0; e < 8; ++e)
                if (e == bi) sc[e] = -INFINITY;   // static-index knockout
        }

        const float mx = val[0];
        float ex[4], se = 0.f;
#pragma unroll
        for (int k = 0; k < 4; ++k) { ex[k] = expf(val[k] - mx); se += ex[k]; }
        const float inv = 1.f / se;

        float Et[4] = {0.f, 0.f, 0.f, 0.f};
#pragma unroll
        for (int k = 0; k < 4; ++k) {
            const float wgt = ex[k] * inv;
#pragma unroll
            for (int r = 0; r < 4; ++r)
                Et[r] = fmaf(wgt, expert_vectors[idx[k] * 4 + r], Et[r]);
        }
#pragma unroll
        for (int r = 0; r < 4; ++r) {
            const float h = sv[8 + r] + Et[r];
            const float g = 0.5f * h * (1.f + erff(h * 0.70710678118654752f));
            hsh[tid][r] = g * SCALEF;            // fold SCALING here
        }
    }
    __syncthreads();

    // streaming write phase: 16 tokens × 16 KB rows, nontemporal
#pragma unroll
    for (int tk = 0; tk < TPB2; ++tk) {
        const float h0 = hsh[tk][0], h1 = hsh[tk][1],
                    h2 = hsh[tk][2], h3 = hsh[tk][3];
        f4* __restrict__ o4 = (f4*)out + (size_t)(tok0 + tk) * 1024;
#pragma unroll
        for (int i = 0; i < 4; ++i) {
            f4 v;
            v[0] = Bc[i][0][0] * h0 + Bc[i][0][1] * h1 + Bc[i][0][2] * h2 + Bc[i][0][3] * h3;
            v[1] = Bc[i][1][0] * h0 + Bc[i][1][1] * h1 + Bc[i][1][2] * h2 + Bc[i][1][3] * h3;
            v[2] = Bc[i][2][0] * h0 + Bc[i][2][1] * h1 + Bc[i][2][2] * h2 + Bc[i][2][3] * h3;
            v[3] = Bc[i][3][0] * h0 + Bc[i][3][1] * h1 + Bc[i][3][2] * h2 + Bc[i][3][3] * h3;
            __builtin_nontemporal_store(v, &o4[i * 256 + tid]);
        }
    }
}

extern "C" void kernel_launch(void* const* d_in, const int* in_sizes, int n_in,
                              void* d_out, int out_size, void* d_ws, size_t ws_size,
                              hipStream_t stream) {
    const float* x        = (const float*)d_in[0];
    const float* A_w      = (const float*)d_in[1];
    const float* B_w      = (const float*)d_in[2];
    const float* router_w = (const float*)d_in[3];
    const float* ev       = (const float*)d_in[4];
    float* out            = (float*)d_out;
    float* s12            = (float*)d_ws;    // 16384 * 12 * 4 B = 768 KB

    k1_scores<<<NBLK1, 256, 0, stream>>>(x, A_w, router_w, s12);
    k2_out  <<<NBLK2, 256, 0, stream>>>(s12, B_w, ev, out);
}

// Round 6
// 169.764 us; speedup vs baseline: 1.0092x; 1.0092x over previous
//
#include <hip/hip_runtime.h>
#include <cmath>

typedef float f4 __attribute__((ext_vector_type(4)));

#define SCALEF 8.0f   // alpha/rank = 32/4

// ---- k1: per token, 12 dots + top4/softmax/gelu; writes h (f4) ------------
// 4096 blocks x 256 thr, one-shot 4 tokens/block. Weights stream from L2
// with a 5-slot rotation, 4 rows in flight (no WAR on the slot being read).
__global__ __launch_bounds__(256, 2) void k1_scores(
    const float* __restrict__ x,
    const float* __restrict__ A_w,
    const float* __restrict__ router_w,
    const float* __restrict__ expert_vectors,
    float* __restrict__ hbuf)
{
    const int tid  = threadIdx.x;
    const int tok0 = blockIdx.x * 4;
    const int wid  = tid >> 6, lane = tid & 63;

    const f4* __restrict__ x4 = (const f4*)x;        // [ntok][1024]
    const f4* __restrict__ r4 = (const f4*)router_w; // [8][1024]
    const f4* __restrict__ a4 = (const f4*)A_w;      // [4][1024]

    __shared__ float red[4][48];

    // all x loads up front (16 independent HBM loads in flight), p-major so
    // row-0 FMA operands complete first
    f4 xv[16];
#pragma unroll
    for (int p = 0; p < 4; ++p)
#pragma unroll
        for (int tk = 0; tk < 4; ++tk)
            xv[tk * 4 + p] = __builtin_nontemporal_load(
                &x4[(size_t)(tok0 + tk) * 1024 + p * 256 + tid]);

#define ROWPTR(W) ((W) < 8 ? (r4 + (size_t)(W) * 1024) : (a4 + (size_t)((W) - 8) * 1024))
    f4 wbuf[5][4];   // 5-slot rotation; all indices compile-time
#pragma unroll
    for (int w = 0; w < 4; ++w)
#pragma unroll
        for (int p = 0; p < 4; ++p)
            wbuf[w][p] = ROWPTR(w)[p * 256 + tid];

    float acc[4][12];
#pragma unroll
    for (int tk = 0; tk < 4; ++tk)
#pragma unroll
        for (int w = 0; w < 12; ++w) acc[tk][w] = 0.f;

#pragma unroll
    for (int w = 0; w < 12; ++w) {
        // issue row w+4 first (into a slot nobody reads this iter: no WAR)
        if (w + 4 < 12) {
            const f4* __restrict__ rp = ROWPTR(w + 4);
#pragma unroll
            for (int p = 0; p < 4; ++p)
                wbuf[(w + 4) % 5][p] = rp[p * 256 + tid];
        }
#pragma unroll
        for (int p = 0; p < 4; ++p) {
            const f4 wv = wbuf[w % 5][p];
#pragma unroll
            for (int tk = 0; tk < 4; ++tk) {
                acc[tk][w] = fmaf(xv[tk * 4 + p][0], wv[0], acc[tk][w]);
                acc[tk][w] = fmaf(xv[tk * 4 + p][1], wv[1], acc[tk][w]);
                acc[tk][w] = fmaf(xv[tk * 4 + p][2], wv[2], acc[tk][w]);
                acc[tk][w] = fmaf(xv[tk * 4 + p][3], wv[3], acc[tk][w]);
            }
        }
    }
#undef ROWPTR

    // wave butterfly
#pragma unroll
    for (int tk = 0; tk < 4; ++tk)
#pragma unroll
        for (int w = 0; w < 12; ++w) {
            float v = acc[tk][w];
#pragma unroll
            for (int m = 1; m < 64; m <<= 1) v += __shfl_xor(v, m, 64);
            acc[tk][w] = v;
        }
    if (lane == 0) {
#pragma unroll
        for (int tk = 0; tk < 4; ++tk)
#pragma unroll
            for (int w = 0; w < 12; ++w) red[wid][tk * 12 + w] = acc[tk][w];
    }
    __syncthreads();   // the only barrier

    // all-lane cross-wave sum (broadcast f4 reads; conflict-free)
    const f4* __restrict__ rr = (const f4*)&red[0][0];   // [4][12] f4
#pragma unroll
    for (int tk = 0; tk < 4; ++tk)
#pragma unroll
        for (int k = 0; k < 3; ++k) {
            const f4 s = rr[0 * 12 + tk * 3 + k] + rr[1 * 12 + tk * 3 + k] +
                         rr[2 * 12 + tk * 3 + k] + rr[3 * 12 + tk * 3 + k];
            acc[tk][4 * k + 0] = s[0];
            acc[tk][4 * k + 1] = s[1];
            acc[tk][4 * k + 2] = s[2];
            acc[tk][4 * k + 3] = s[3];
        }

    // all-lane redundant epilogue (no divergence until the 4-store tail)
    f4 hout[4];
#pragma unroll
    for (int tk = 0; tk < 4; ++tk) {
        float sc[8];
#pragma unroll
        for (int e = 0; e < 8; ++e) sc[e] = acc[tk][e];

        int   idx[4];
        float val[4];
#pragma unroll
        for (int k = 0; k < 4; ++k) {
            int bi = 0; float bv = sc[0];
#pragma unroll
            for (int e = 1; e < 8; ++e)
                if (sc[e] > bv) { bv = sc[e]; bi = e; }
            idx[k] = bi; val[k] = bv;
#pragma unroll
            for (int e = 0; e < 8; ++e)
                if (e == bi) sc[e] = -INFINITY;   // static-index knockout
        }

        const float mx = val[0];
        float ex[4], se = 0.f;
#pragma unroll
        for (int k = 0; k < 4; ++k) { ex[k] = expf(val[k] - mx); se += ex[k]; }
        const float inv = 1.f / se;

        float Et[4] = {0.f, 0.f, 0.f, 0.f};
#pragma unroll
        for (int k = 0; k < 4; ++k) {
            const float wgt = ex[k] * inv;
#pragma unroll
            for (int r = 0; r < 4; ++r)
                Et[r] = fmaf(wgt, expert_vectors[idx[k] * 4 + r], Et[r]);
        }
#pragma unroll
        for (int r = 0; r < 4; ++r) {
            const float hv = acc[tk][8 + r] + Et[r];
            hout[tk][r] = SCALEF * 0.5f * hv *
                          (1.f + erff(hv * 0.70710678118654752f));
        }
    }

    if (tid < 4) {
        const f4 o = (tid == 0) ? hout[0] : (tid == 1) ? hout[1]
                   : (tid == 2) ? hout[2] : hout[3];
        ((f4*)hbuf)[tok0 + tid] = o;
    }
}

// ---- k2: out[t][4c+i] = dot(B[4c+i], h[t]) — fill-shaped streaming --------
// ntok*4/4... grid = ntok blocks: b>>2 = token quad, b&3 = column quarter.
// No LDS, no barriers, ~40 VGPR, 4 nontemporal 16B stores/thread.
__global__ __launch_bounds__(256, 8) void k2_out(
    const float* __restrict__ hbuf,
    const float* __restrict__ B_w,
    float* __restrict__ out)
{
    const int tid = threadIdx.x;
    const int tq  = blockIdx.x >> 2;
    const int cq  = blockIdx.x & 3;
    const int c   = cq * 256 + tid;           // out f4-chunk within a row

    const f4* __restrict__ b4 = (const f4*)B_w;   // row o = f4 o
    const f4* __restrict__ h4 = (const f4*)hbuf;

    const f4 B0 = b4[4 * c + 0], B1 = b4[4 * c + 1],
             B2 = b4[4 * c + 2], B3 = b4[4 * c + 3];

    const int tok0 = tq * 4;
    const f4 h0 = h4[tok0 + 0], h1 = h4[tok0 + 1],
             h2 = h4[tok0 + 2], h3 = h4[tok0 + 3];

    f4* __restrict__ o4 = (f4*)out;
#pragma unroll
    for (int tk = 0; tk < 4; ++tk) {
        const f4 hh = (tk == 0) ? h0 : (tk == 1) ? h1 : (tk == 2) ? h2 : h3;
        f4 v;
        v[0] = B0[0] * hh[0] + B0[1] * hh[1] + B0[2] * hh[2] + B0[3] * hh[3];
        v[1] = B1[0] * hh[0] + B1[1] * hh[1] + B1[2] * hh[2] + B1[3] * hh[3];
        v[2] = B2[0] * hh[0] + B2[1] * hh[1] + B2[2] * hh[2] + B2[3] * hh[3];
        v[3] = B3[0] * hh[0] + B3[1] * hh[1] + B3[2] * hh[2] + B3[3] * hh[3];
        __builtin_nontemporal_store(v, &o4[(size_t)(tok0 + tk) * 1024 + c]);
    }
}

extern "C" void kernel_launch(void* const* d_in, const int* in_sizes, int n_in,
                              void* d_out, int out_size, void* d_ws, size_t ws_size,
                              hipStream_t stream) {
    const float* x        = (const float*)d_in[0];
    const float* A_w      = (const float*)d_in[1];
    const float* B_w      = (const float*)d_in[2];
    const float* router_w = (const float*)d_in[3];
    const float* ev       = (const float*)d_in[4];
    float* out            = (float*)d_out;
    float* hbuf           = (float*)d_ws;     // ntok * 4 floats = 256 KB

    const int ntok = in_sizes[0] / 4096;      // 16384
    k1_scores<<<ntok / 4, 256, 0, stream>>>(x, A_w, router_w, ev, hbuf);
    k2_out   <<<ntok,     256, 0, stream>>>(hbuf, B_w, out);
}